// Round 1
// baseline (578.956 us; speedup 1.0000x reference)
//
#include <hip/hip_runtime.h>
#include <hip/hip_bf16.h>
#include <cstdint>
#include <cstddef>

#define UNITS 1024
#define BDIM 32
#define TDIM 2048
#define M_TOT (BDIM*TDIM)   /* 65536 */
#define KDIM UNITS
#define NDIM UNITS
#define NPART 4              /* score partials = n-tiles of 256 */

#define K2LOG2E 2.885390081777927f   /* 2*log2(e): tanh(x) = 1 - 2/(exp2(x*K2LOG2E)+1) */

typedef __attribute__((ext_vector_type(8))) short bf16x8;           // 8 bf16 = 4 VGPRs
typedef __attribute__((ext_vector_type(8))) unsigned short ushort8;
typedef __attribute__((ext_vector_type(4))) float f32x4;

__device__ __forceinline__ unsigned short f2bf(float f) {
  unsigned u = __float_as_uint(f);
  u += 0x7fffu + ((u >> 16) & 1u);          // round-to-nearest-even
  return (unsigned short)(u >> 16);
}
__device__ __forceinline__ float bf2f(unsigned short h) {
  return __uint_as_float(((unsigned)h) << 16);
}

// ---------------- fp32 -> bf16 conversion (8 floats / thread / iter) --------
__global__ __launch_bounds__(256) void cvt_kernel(const float* __restrict__ src,
                                                  ushort* __restrict__ dst, int n8) {
  int i = blockIdx.x * blockDim.x + threadIdx.x;
  int stride = gridDim.x * blockDim.x;
  const float4* s4 = (const float4*)src;
  ushort8* d8 = (ushort8*)dst;
  for (; i < n8; i += stride) {
    float4 a = s4[2*i], b = s4[2*i+1];
    ushort8 o;
    o[0] = f2bf(a.x); o[1] = f2bf(a.y); o[2] = f2bf(a.z); o[3] = f2bf(a.w);
    o[4] = f2bf(b.x); o[5] = f2bf(b.y); o[6] = f2bf(b.z); o[7] = f2bf(b.w);
    d8[i] = o;                                   // one 16B store
  }
}

// ---------------- c[b,v] = W1_b[v] + W2_b[v] + dot(W2[v,:], hidden[b,:]) ----
__global__ __launch_bounds__(64) void prep_c_kernel(const float* __restrict__ W2w,
                                                    const float* __restrict__ hidden,
                                                    const float* __restrict__ W1b,
                                                    const float* __restrict__ W2b,
                                                    float* __restrict__ c) {
  int v = blockIdx.x;
  int l = threadIdx.x;
  float acc[BDIM];
  #pragma unroll
  for (int b = 0; b < BDIM; b++) acc[b] = 0.f;
  for (int u0 = 0; u0 < UNITS; u0 += 64) {
    float w = W2w[v*UNITS + u0 + l];           // coalesced over lanes
    #pragma unroll
    for (int b = 0; b < BDIM; b++) acc[b] += w * hidden[b*UNITS + u0 + l];
  }
  float bias = W1b[v] + W2b[v];
  #pragma unroll
  for (int b = 0; b < BDIM; b++) {
    float s = acc[b];
    #pragma unroll
    for (int off = 32; off > 0; off >>= 1) s += __shfl_xor(s, off);
    if (l == 0) c[b*UNITS + v] = s + bias;
  }
}

// ---------------- fused GEMM + tanh + V-dot -> partial scores ---------------
// 256x256 tile, BK=64, 8 waves (2Mx4N, per-wave 128x64 = acc[8][4]).
// 128 KB LDS double-buffer, counted-vmcnt pipeline with raw s_barrier
// (never drains vmcnt to 0 in the main loop -> loads span barriers).
// LDS uses the 8-slot rotation swizzle (phys = (slot + row) & 7), staged via
// pre-swizzled GLOBAL source + linear global_load_lds dest: 0 bank conflicts.
// Grid 1024 = 256 m-tiles x 4 n-tiles (nt-minor: each XCD pins one 512 KB
// B n-panel in L2; same-m-tile blocks dispatch adjacently for L3 A reuse).
#define GLL(g, l) __builtin_amdgcn_global_load_lds(                              \
    (const __attribute__((address_space(1))) void*)(g),                          \
    (__attribute__((address_space(3))) void*)(l), 16, 0, 0)

__global__ __launch_bounds__(512, 2) void gemm_score_kernel(
    const ushort* __restrict__ A,   // M x K bf16 (row-major)
    const ushort* __restrict__ W,   // N x K bf16 (row-major)
    const float* __restrict__ c,    // B x N
    const float* __restrict__ Vw,   // N
    float* __restrict__ score)      // NPART x M partials (each written once)
{
  __shared__ ushort sh[2][2][16384];   // 128 KB: [buf][A|B][256 rows x 64 k]
  ushort* shb = &sh[0][0][0];

  const int nt = blockIdx.x & 3;            // n-tile 0..3
  const int m0 = (blockIdx.x >> 2) * 256;
  const int n0 = nt * 256;
  const int bb = m0 >> 11;                  // 256 rows share one b (T=2048)
  const int tid = threadIdx.x;
  const int wave = tid >> 6;
  const int l = tid & 63;
  const int lrow = l & 15;                  // n within 16x16 frag
  const int lq = l >> 4;                    // quad
  const int wm = (wave >> 2) * 128;         // wave m-offset (0 / 128)
  const int wn = (wave & 3) * 64;           // wave n-offset (0/64/128/192)

  // staging: thread -> (row = t>>3 (+64j), phys slot = t&7); content
  // global k-slot s = (phys - row) & 7  (8-slot rotation swizzle; row step 64
  // preserves rotation since 64 % 8 == 0)
  const int srow = tid >> 3;                              // 0..63
  const int s_g  = ((tid & 7) - srow) & 7;                // global slot staged
  // fragment read: phys p = (ksub*4 + lq + row) & 7 ; row mod 8 == lrow mod 8
  const int p0 = ((lq + lrow) & 7) * 8;                   // ksub 0, ushort off
  const int p1 = ((lq + lrow + 4) & 7) * 8;               // ksub 1
  const int aoff = (wm + lrow) * 64;
  const int boff = (wn + lrow) * 64;

  // global staging pointers (advance 64 elems per staged K-tile)
  const ushort* gA0 = A + (size_t)(m0 + srow) * KDIM + s_g * 8;
  const ushort* gA1 = gA0 + (size_t)64 * KDIM;
  const ushort* gA2 = gA0 + (size_t)128 * KDIM;
  const ushort* gA3 = gA0 + (size_t)192 * KDIM;
  const ushort* gB0 = W + (size_t)(n0 + srow) * KDIM + s_g * 8;
  const ushort* gB1 = gB0 + (size_t)64 * KDIM;
  const ushort* gB2 = gB0 + (size_t)128 * KDIM;
  const ushort* gB3 = gB0 + (size_t)192 * KDIM;

  f32x4 acc[8][4];
  #pragma unroll
  for (int i = 0; i < 8; i++)
    #pragma unroll
    for (int j = 0; j < 4; j++) acc[i][j] = (f32x4)0.f;

  // stage one full K-tile (A 32KB + B 32KB) into buf: 8 x global_load_lds
  auto STAGE = [&](int buf) {
    ushort* dA = shb + buf * 32768 + wave * 512;   // wave-uniform; HW adds lane*16B
    ushort* dB = dA + 16384;
    GLL(gA0, dA);          GLL(gA1, dA + 4096);
    GLL(gA2, dA + 8192);   GLL(gA3, dA + 12288);
    GLL(gB0, dB);          GLL(gB1, dB + 4096);
    GLL(gB2, dB + 8192);   GLL(gB3, dB + 12288);
    gA0 += 64; gA1 += 64; gA2 += 64; gA3 += 64;
    gB0 += 64; gB1 += 64; gB2 += 64; gB3 += 64;
  };

  // one K-tile of MFMA: 2 ksub x (12 ds_read_b128 + 32 mfma)
  auto COMPUTE = [&](int buf) {
    const ushort* Ab = shb + buf * 32768;
    const ushort* Bb = Ab + 16384;
    {
      bf16x8 a[8], b[4];
      #pragma unroll
      for (int i = 0; i < 8; i++) a[i] = *(const bf16x8*)(Ab + aoff + i * 1024 + p0);
      #pragma unroll
      for (int j = 0; j < 4; j++) b[j] = *(const bf16x8*)(Bb + boff + j * 1024 + p0);
      __builtin_amdgcn_s_setprio(1);
      #pragma unroll
      for (int i = 0; i < 8; i++)
        #pragma unroll
        for (int j = 0; j < 4; j++)
          acc[i][j] = __builtin_amdgcn_mfma_f32_16x16x32_bf16(a[i], b[j], acc[i][j], 0, 0, 0);
      __builtin_amdgcn_s_setprio(0);
    }
    {
      bf16x8 a[8], b[4];
      #pragma unroll
      for (int i = 0; i < 8; i++) a[i] = *(const bf16x8*)(Ab + aoff + i * 1024 + p1);
      #pragma unroll
      for (int j = 0; j < 4; j++) b[j] = *(const bf16x8*)(Bb + boff + j * 1024 + p1);
      __builtin_amdgcn_s_setprio(1);
      #pragma unroll
      for (int i = 0; i < 8; i++)
        #pragma unroll
        for (int j = 0; j < 4; j++)
          acc[i][j] = __builtin_amdgcn_mfma_f32_16x16x32_bf16(a[i], b[j], acc[i][j], 0, 0, 0);
      __builtin_amdgcn_s_setprio(0);
    }
  };

  // ---- pipeline: 16 K-tiles, depth-2, vmcnt never drained to 0 mid-loop ----
  STAGE(0);                                            // tile 0
  STAGE(1);                                            // tile 1 (16 in flight)
  asm volatile("s_waitcnt vmcnt(8)" ::: "memory");     // tile 0 landed (this wave)
  __builtin_amdgcn_s_barrier();                        // all waves: tile 0 ready
  int cur = 0;
  #pragma unroll 1
  for (int kt = 0; kt < 14; ++kt) {
    COMPUTE(cur);                                      // tile kt (stage kt+1 in flight)
    asm volatile("s_waitcnt lgkmcnt(0)" ::: "memory"); // own LDS reads drained
    __builtin_amdgcn_s_barrier();                      // all waves done with buf cur
    STAGE(cur);                                        // tile kt+2 -> buf cur
    asm volatile("s_waitcnt vmcnt(8)" ::: "memory");   // tile kt+1 landed; kt+2 flies on
    __builtin_amdgcn_s_barrier();                      // all waves: tile kt+1 ready
    cur ^= 1;
  }
  COMPUTE(cur);                                        // tile 14 (buf 0)
  asm volatile("s_waitcnt lgkmcnt(0)" ::: "memory");
  __builtin_amdgcn_s_barrier();
  asm volatile("s_waitcnt vmcnt(0)" ::: "memory");     // drain tile 15's stage
  __builtin_amdgcn_s_barrier();
  COMPUTE(cur ^ 1);                                    // tile 15 (buf 1)

  // epilogue: score_partial = sum_n vw * tanh(C + c) = vws - 2 * sum vw*sigma
  float vw4[4], ck4[4];
  float vws = 0.f;
  #pragma unroll
  for (int j = 0; j < 4; j++) {
    int n = n0 + wn + j * 16 + lrow;
    float v = Vw[n];
    vw4[j] = v;
    vws += v;
    ck4[j] = c[bb * NDIM + n] * K2LOG2E;
  }
  float sacc[8][4];
  #pragma unroll
  for (int i = 0; i < 8; i++)
    #pragma unroll
    for (int r = 0; r < 4; r++) sacc[i][r] = 0.f;
  #pragma unroll
  for (int i = 0; i < 8; i++)
    #pragma unroll
    for (int j = 0; j < 4; j++)
      #pragma unroll
      for (int r = 0; r < 4; r++) {
        float t = __builtin_fmaf(acc[i][j][r], K2LOG2E, ck4[j]);
        float e = __builtin_amdgcn_exp2f(t);        // inf->rcp 0 (tanh=1); 0 (tanh=-1)
        float rr = __builtin_amdgcn_rcpf(e + 1.f);
        sacc[i][r] = __builtin_fmaf(vw4[j], rr, sacc[i][r]);
      }

  // reduce over 16 n-lanes of each quad, then across the 4 n-waves via LDS.
  // sred overlays buf0-A (last read at tile 14, two barriers ago; tile-15
  // readers touch only buf1) -> no extra barrier needed before the writes.
  float* sred = (float*)shb;                      // 8 waves x 128 rows = 4 KB
  #pragma unroll
  for (int i = 0; i < 8; i++)
    #pragma unroll
    for (int r = 0; r < 4; r++) {
      float s = vws - 2.f * sacc[i][r];
      s += __shfl_xor(s, 1);
      s += __shfl_xor(s, 2);
      s += __shfl_xor(s, 4);
      s += __shfl_xor(s, 8);
      if (lrow == 0) sred[wave * 128 + i * 16 + lq * 4 + r] = s;
    }
  __syncthreads();
  if (tid < 256) {
    int mh = tid >> 7;            // which 128-row half -> waves mh*4 .. mh*4+3
    int ml = tid & 127;
    float v = sred[mh * 512 + ml] + sred[mh * 512 + 128 + ml]
            + sred[mh * 512 + 256 + ml] + sred[mh * 512 + 384 + ml];
    score[(size_t)nt * M_TOT + m0 + tid] = v;
  }
}

// ---------------- softmax over T per b; sums the NPART partial slices ------
__global__ __launch_bounds__(256) void softmax_kernel(float* __restrict__ sc,
                                                      float* __restrict__ wout) {
  const int b = blockIdx.x;
  const int tid = threadIdx.x;
  float4* s4 = (float4*)(sc + (size_t)b * TDIM);
  float4 v0 = s4[2*tid], v1 = s4[2*tid+1];
  #pragma unroll
  for (int k = 1; k < NPART; k++) {
    const float4* p4 = (const float4*)(sc + (size_t)k * M_TOT + (size_t)b * TDIM);
    float4 u0 = p4[2*tid], u1 = p4[2*tid+1];
    v0.x += u0.x; v0.y += u0.y; v0.z += u0.z; v0.w += u0.w;
    v1.x += u1.x; v1.y += u1.y; v1.z += u1.z; v1.w += u1.w;
  }
  float mx = fmaxf(fmaxf(fmaxf(v0.x,v0.y),fmaxf(v0.z,v0.w)),
                   fmaxf(fmaxf(v1.x,v1.y),fmaxf(v1.z,v1.w)));
  #pragma unroll
  for (int off = 32; off > 0; off >>= 1) mx = fmaxf(mx, __shfl_xor(mx, off));
  __shared__ float redm[4];
  __shared__ float reds[4];
  if ((tid & 63) == 0) redm[tid >> 6] = mx;
  __syncthreads();
  mx = fmaxf(fmaxf(redm[0], redm[1]), fmaxf(redm[2], redm[3]));
  v0.x = __expf(v0.x - mx); v0.y = __expf(v0.y - mx);
  v0.z = __expf(v0.z - mx); v0.w = __expf(v0.w - mx);
  v1.x = __expf(v1.x - mx); v1.y = __expf(v1.y - mx);
  v1.z = __expf(v1.z - mx); v1.w = __expf(v1.w - mx);
  float sum = v0.x+v0.y+v0.z+v0.w+v1.x+v1.y+v1.z+v1.w;
  #pragma unroll
  for (int off = 32; off > 0; off >>= 1) sum += __shfl_xor(sum, off);
  if ((tid & 63) == 0) reds[tid >> 6] = sum;
  __syncthreads();
  sum = reds[0]+reds[1]+reds[2]+reds[3];
  float inv = 1.f / sum;
  v0.x *= inv; v0.y *= inv; v0.z *= inv; v0.w *= inv;
  v1.x *= inv; v1.y *= inv; v1.z *= inv; v1.w *= inv;
  s4[2*tid] = v0; s4[2*tid+1] = v1;                 // ws copy for context pass
  float4* w4 = (float4*)(wout + (size_t)b * TDIM);  // d_out weights
  w4[2*tid] = v0; w4[2*tid+1] = v1;
}

// ---------------- context[b,u] = sum_t w[b,t]*x[b,t,u]  (exact, no atomics) -
// grid (8 u-chunks of 128, 32 b); 256 threads = 16 u-threads x 16 t-rows
__global__ __launch_bounds__(256) void context_kernel(const ushort* __restrict__ xb,
                                                      const float* __restrict__ wgt,
                                                      float* __restrict__ ctx) {
  const int uc = blockIdx.x;
  const int b = blockIdx.y;
  const int tid = threadIdx.x;
  __shared__ float wl[TDIM];
  {
    const float4* wsrc = (const float4*)(wgt + (size_t)b * TDIM);
    float4* wdst = (float4*)wl;
    wdst[tid] = wsrc[tid];
    wdst[tid + 256] = wsrc[tid + 256];
  }
  __syncthreads();
  const int ut = tid & 15;         // 16 threads x ushort8 = 128 u
  const int tr = tid >> 4;         // 16 t-rows per sweep
  const ushort* xp = xb + (size_t)b * TDIM * UNITS + uc * 128 + ut * 8;
  float a8[8];
  #pragma unroll
  for (int e = 0; e < 8; e++) a8[e] = 0.f;
  for (int t = tr; t < TDIM; t += 64) {            // 4-way unrolled over stride 16
    ushort8 x0 = *(const ushort8*)(xp + (size_t)(t     ) * UNITS);
    ushort8 x1 = *(const ushort8*)(xp + (size_t)(t + 16) * UNITS);
    ushort8 x2 = *(const ushort8*)(xp + (size_t)(t + 32) * UNITS);
    ushort8 x3 = *(const ushort8*)(xp + (size_t)(t + 48) * UNITS);
    float w0 = wl[t], w1 = wl[t+16], w2 = wl[t+32], w3 = wl[t+48];
    #pragma unroll
    for (int e = 0; e < 8; e++) {
      a8[e] += w0 * bf2f(x0[e]);
      a8[e] += w1 * bf2f(x1[e]);
      a8[e] += w2 * bf2f(x2[e]);
      a8[e] += w3 * bf2f(x3[e]);
    }
  }
  // reduce over the 4 t-rows within each wave
  #pragma unroll
  for (int e = 0; e < 8; e++) {
    a8[e] += __shfl_xor(a8[e], 16);
    a8[e] += __shfl_xor(a8[e], 32);
  }
  __shared__ float red[512];
  const int wave = tid >> 6;
  const int l = tid & 63;
  if (l < 16) {
    #pragma unroll
    for (int e = 0; e < 8; e++) red[wave * 128 + l * 8 + e] = a8[e];
  }
  __syncthreads();
  if (tid < 128) {
    float v = red[tid] + red[128 + tid] + red[256 + tid] + red[384 + tid];
    ctx[(size_t)b * UNITS + uc * 128 + tid] = v;
  }
}

extern "C" void kernel_launch(void* const* d_in, const int* in_sizes, int n_in,
                              void* d_out, int out_size, void* d_ws, size_t ws_size,
                              hipStream_t stream) {
  const float* x   = (const float*)d_in[0];
  const float* hid = (const float*)d_in[1];
  const float* W1w = (const float*)d_in[2];
  const float* W1b = (const float*)d_in[3];
  const float* W2w = (const float*)d_in[4];
  const float* W2b = (const float*)d_in[5];
  const float* Vw  = (const float*)d_in[6];
  // d_in[7] (V_b) intentionally unused: softmax is shift-invariant.
  float* out = (float*)d_out;

  char* ws = (char*)d_ws;
  ushort* xb   = (ushort*)ws;                                        // 128 MB
  ushort* w1b  = (ushort*)(ws + (size_t)M_TOT*KDIM*2);               // 2 MB
  float*  cbuf = (float*)(ws + (size_t)M_TOT*KDIM*2 + (size_t)NDIM*KDIM*2); // 128 KB
  float*  score= (float*)((char*)cbuf + (size_t)BDIM*NDIM*4);        // NPART x 256 KB partials

  cvt_kernel<<<4096, 256, 0, stream>>>(x, xb, M_TOT*KDIM/8);
  cvt_kernel<<<512, 256, 0, stream>>>(W1w, w1b, NDIM*KDIM/8);
  prep_c_kernel<<<NDIM, 64, 0, stream>>>(W2w, hid, W1b, W2b, cbuf);
  gemm_score_kernel<<<M_TOT/256 * NPART, 512, 0, stream>>>(xb, w1b, cbuf, Vw, score);
  softmax_kernel<<<BDIM, 256, 0, stream>>>(score, out + (size_t)BDIM*UNITS);
  context_kernel<<<dim3(8, BDIM), 256, 0, stream>>>(xb, score, out);
}

// Round 3
// 562.788 us; speedup vs baseline: 1.0287x; 1.0287x over previous
//
#include <hip/hip_runtime.h>
#include <hip/hip_bf16.h>
#include <cstdint>
#include <cstddef>

#define UNITS 1024
#define BDIM 32
#define TDIM 2048
#define M_TOT (BDIM*TDIM)   /* 65536 */
#define KDIM UNITS
#define NDIM UNITS
#define NPART 4              /* score partials = n-tiles of 256 */

#define K2LOG2E 2.885390081777927f   /* 2*log2(e): tanh(x) = 1 - 2/(exp2(x*K2LOG2E)+1) */

typedef __attribute__((ext_vector_type(8))) short bf16x8;           // 8 bf16 = 4 VGPRs
typedef __attribute__((ext_vector_type(8))) unsigned short ushort8;
typedef __attribute__((ext_vector_type(4))) float f32x4;

__device__ __forceinline__ unsigned short f2bf(float f) {
  unsigned u = __float_as_uint(f);
  u += 0x7fffu + ((u >> 16) & 1u);          // round-to-nearest-even
  return (unsigned short)(u >> 16);
}
__device__ __forceinline__ float bf2f(unsigned short h) {
  return __uint_as_float(((unsigned)h) << 16);
}

// ---------------- fp32 -> bf16 conversion (8 floats / thread / iter) --------
__global__ __launch_bounds__(256) void cvt_kernel(const float* __restrict__ src,
                                                  ushort* __restrict__ dst, int n8) {
  int i = blockIdx.x * blockDim.x + threadIdx.x;
  int stride = gridDim.x * blockDim.x;
  const float4* s4 = (const float4*)src;
  ushort8* d8 = (ushort8*)dst;
  for (; i < n8; i += stride) {
    float4 a = s4[2*i], b = s4[2*i+1];
    ushort8 o;
    o[0] = f2bf(a.x); o[1] = f2bf(a.y); o[2] = f2bf(a.z); o[3] = f2bf(a.w);
    o[4] = f2bf(b.x); o[5] = f2bf(b.y); o[6] = f2bf(b.z); o[7] = f2bf(b.w);
    d8[i] = o;                                   // one 16B store
  }
}

// ---------------- c[b,v] = W1_b[v] + W2_b[v] + dot(W2[v,:], hidden[b,:]) ----
__global__ __launch_bounds__(64) void prep_c_kernel(const float* __restrict__ W2w,
                                                    const float* __restrict__ hidden,
                                                    const float* __restrict__ W1b,
                                                    const float* __restrict__ W2b,
                                                    float* __restrict__ c) {
  int v = blockIdx.x;
  int l = threadIdx.x;
  float acc[BDIM];
  #pragma unroll
  for (int b = 0; b < BDIM; b++) acc[b] = 0.f;
  for (int u0 = 0; u0 < UNITS; u0 += 64) {
    float w = W2w[v*UNITS + u0 + l];           // coalesced over lanes
    #pragma unroll
    for (int b = 0; b < BDIM; b++) acc[b] += w * hidden[b*UNITS + u0 + l];
  }
  float bias = W1b[v] + W2b[v];
  #pragma unroll
  for (int b = 0; b < BDIM; b++) {
    float s = acc[b];
    #pragma unroll
    for (int off = 32; off > 0; off >>= 1) s += __shfl_xor(s, off);
    if (l == 0) c[b*UNITS + v] = s + bias;
  }
}

// ---------------- fused GEMM + tanh + V-dot -> partial scores ---------------
// 256x256 tile, 8 waves (2Mx4N, per-wave 128x64 = acc[8][4]), fine-grained
// 8-phase pipeline (T3+T4+T5): each phase = {4-8 ds_read_b128, stage one
// 16KB k-half (2 global_load_lds), s_barrier, setprio(1), 16 MFMA,
// setprio(0), [vmcnt(8) checkpoint], s_barrier, sched_barrier(0)}.
// vmcnt is never drained to 0 in the main loop; 4 k-halves stay in flight.
//
// LDS = two 4-slot rings (A, B) of 16KB k-halves (256 rows x 32 k).
// Swizzle: phys k-slot = (k_slot + (row>>1)) & 3 -> every 16-lane read group
// spreads over 8 bank-quads at exactly 2-way aliasing (2-way is free, m136).
// Staged via pre-swizzled global source + linear gll dest (both-sides rule).
//
// Lifetime ledger (phases of tile t are global 4t+1..4t+4; stage(τ,half)
// issues at phase: A0:4τ-5  B0:4τ-4  A1:4τ-3  B1:4τ-2; reads: A0,B0 @4τ+1
// (b regs persist to 4τ+2), A1,B1 @4τ+3):
//   - slot overwrite is always >=1 closing barrier after its last reader
//   - vmcnt(8)+barrier checkpoints at phases 4t+2, 4t+4 guarantee every
//     k-half has landed >=1 phase before its first read (8 = 2 gll x 4
//     in-flight k-halves)
// Grid 1024 = 256 m-tiles x 4 n-tiles (nt-minor: XCD L2 pins one B n-panel).
#define GLL(g, l) __builtin_amdgcn_global_load_lds(                              \
    (const __attribute__((address_space(1))) void*)(g),                          \
    (__attribute__((address_space(3))) void*)(l), 16, 0, 0)

__global__ __launch_bounds__(512, 2) void gemm_score_kernel(
    const ushort* __restrict__ A,   // M x K bf16 (row-major)
    const ushort* __restrict__ W,   // N x K bf16 (row-major)
    const float* __restrict__ c,    // B x N
    const float* __restrict__ Vw,   // N
    float* __restrict__ score)      // NPART x M partials (each written once)
{
  __shared__ ushort shb[65536];   // 128 KB: A-ring 4x8192 | B-ring 4x8192 (ushorts)

  const int nt = blockIdx.x & 3;            // n-tile 0..3
  const int m0 = (blockIdx.x >> 2) * 256;
  const int n0 = nt * 256;
  const int bb = m0 >> 11;                  // 256 rows share one b (T=2048)
  const int tid = threadIdx.x;
  const int wave = tid >> 6;
  const int l = tid & 63;
  const int lrow = l & 15;                  // row/col within 16x16 frag
  const int lq = l >> 4;                    // k-quad (8 bf16 each)
  const int wm = (wave >> 2) * 128;         // wave m-offset (0 / 128)
  const int wn = (wave & 3) * 64;           // wave n-offset (0/64/128/192)

  // staging map: gll writes region linearly at ushort off = q*4096 + tid*8
  // -> (row = q*128 + tid>>2, phys = tid&3). Content must be global k-slot
  // s_g = (phys - (row>>1)) & 3  (4-slot rotation; q*64 == 0 mod 4).
  const int s_g = ((tid & 3) - (tid >> 3)) & 3;
  const ushort* sA = A + (size_t)(m0 + (tid >> 2)) * KDIM + s_g * 8;
  const ushort* sB = W + (size_t)(n0 + (tid >> 2)) * KDIM + s_g * 8;

  // fragment read map: lane wants k-slot lq of row (w?+i*16+lrow);
  // phys = (lq + (row>>1)) & 3; wm/2, wn/2, i*8 all == 0 mod 4 -> drop out.
  const int prot = (lq + (lrow >> 1)) & 3;
  const int a_off = (wm + lrow) * 32 + prot * 8;
  const int b_off = (wn + lrow) * 32 + prot * 8;

  f32x4 acc[8][4];
  #pragma unroll
  for (int i = 0; i < 8; i++)
    #pragma unroll
    for (int j = 0; j < 4; j++) acc[i][j] = (f32x4)0.f;

  // stage one k-half (16KB): 2 gll issues of 8KB (q=0: rows 0-127, q=1: 128-255)
  #define STAGE_A(TAU, C) {                                                     \
    const ushort* g_ = sA + (TAU) * 64 + (C) * 32;                              \
    ushort* d_ = shb + ((2*(TAU)+(C)) & 3) * 8192 + wave * 512;                 \
    GLL(g_, d_);                                                                \
    GLL(g_ + (size_t)128 * KDIM, d_ + 4096); }
  #define STAGE_B(TAU, C) {                                                     \
    const ushort* g_ = sB + (TAU) * 64 + (C) * 32;                              \
    ushort* d_ = shb + 32768 + ((2*(TAU)+(C)) & 3) * 8192 + wave * 512;         \
    GLL(g_, d_);                                                                \
    GLL(g_ + (size_t)128 * KDIM, d_ + 4096); }

  bf16x8 bv[4];   // B k-half regs persist across the (ih=0, ih=1) phase pair

  // PHASE: one quadrant (16 MFMA).  IH=0 loads b[0..3]+a[0..3]; IH=1 a[4..7].
  // DO_ST: 0 none, 1 stage-A(ST_TAU,ST_C), 2 stage-B(ST_TAU,ST_C).
  // VM: -1 none, else counted s_waitcnt vmcnt(VM) before closing barrier.
  #define PHASE(TAU, C, IH, VM, DO_ST, ST_TAU, ST_C) {                          \
    const int aslot_ = ((2*(TAU)+(C)) & 3) * 8192;                              \
    const int bslot_ = 32768 + aslot_;                                          \
    bf16x8 av[4];                                                               \
    if ((IH) == 0) {                                                            \
      _Pragma("unroll")                                                         \
      for (int j = 0; j < 4; j++)                                               \
        bv[j] = *(const bf16x8*)(shb + bslot_ + b_off + j * 512);               \
    }                                                                           \
    _Pragma("unroll")                                                           \
    for (int i = 0; i < 4; i++)                                                 \
      av[i] = *(const bf16x8*)(shb + aslot_ + a_off + ((IH)*4 + i) * 512);      \
    if ((DO_ST) == 1) STAGE_A(ST_TAU, ST_C);                                    \
    if ((DO_ST) == 2) STAGE_B(ST_TAU, ST_C);                                    \
    __builtin_amdgcn_s_barrier();                                               \
    __builtin_amdgcn_s_setprio(1);                                              \
    _Pragma("unroll")                                                           \
    for (int i = 0; i < 4; i++)                                                 \
      _Pragma("unroll")                                                         \
      for (int j = 0; j < 4; j++)                                               \
        acc[(IH)*4 + i][j] =                                                    \
          __builtin_amdgcn_mfma_f32_16x16x32_bf16(av[i], bv[j],                 \
                                                  acc[(IH)*4 + i][j], 0, 0, 0); \
    __builtin_amdgcn_s_setprio(0);                                              \
    if ((VM) == 8) asm volatile("s_waitcnt vmcnt(8)" ::: "memory");             \
    if ((VM) == 4) asm volatile("s_waitcnt vmcnt(4)" ::: "memory");             \
    if ((VM) == 0) asm volatile("s_waitcnt vmcnt(0)" ::: "memory");             \
    __builtin_amdgcn_s_barrier();                                               \
    __builtin_amdgcn_sched_barrier(0);                                          \
  }

  // ---- prologue: tile0 (A0,B0,A1,B1) + tile1 (A0,B0) = 12 gll -------------
  STAGE_A(0, 0); STAGE_B(0, 0);
  STAGE_A(0, 1); STAGE_B(0, 1);
  STAGE_A(1, 0); STAGE_B(1, 0);
  asm volatile("s_waitcnt vmcnt(8)" ::: "memory");   // tile0 A0,B0 landed
  __builtin_amdgcn_s_barrier();
  __builtin_amdgcn_sched_barrier(0);

  // ---- main loop: tiles 0..13, 4 phases each ------------------------------
  #pragma unroll 1
  for (int tau = 0; tau < 14; ++tau) {
    PHASE(tau, 0, 0, -1, 1, tau + 1, 1);   // stage A1(tau+1)
    PHASE(tau, 0, 1,  8, 2, tau + 1, 1);   // stage B1(tau+1); ckpt
    PHASE(tau, 1, 0, -1, 1, tau + 2, 0);   // stage A0(tau+2)
    PHASE(tau, 1, 1,  8, 2, tau + 2, 0);   // stage B0(tau+2); ckpt
  }
  // ---- tail: tile 14 (stages tile15 ksub1 only), tile 15 (no stages) ------
  PHASE(14, 0, 0, -1, 1, 15, 1);
  PHASE(14, 0, 1,  8, 2, 15, 1);
  PHASE(14, 1, 0, -1, 0, 0, 0);
  PHASE(14, 1, 1,  4, 0, 0, 0);            // A0(15),B0(15) landed
  PHASE(15, 0, 0, -1, 0, 0, 0);
  PHASE(15, 0, 1,  0, 0, 0, 0);            // A1(15),B1(15) landed
  PHASE(15, 1, 0, -1, 0, 0, 0);
  PHASE(15, 1, 1, -1, 0, 0, 0);

  #undef PHASE
  #undef STAGE_A
  #undef STAGE_B

  // epilogue: score_partial = sum_n vw * tanh(C + c) = vws - 2 * sum vw*sigma
  float vw4[4], ck4[4];
  float vws = 0.f;
  #pragma unroll
  for (int j = 0; j < 4; j++) {
    int n = n0 + wn + j * 16 + lrow;
    float v = Vw[n];
    vw4[j] = v;
    vws += v;
    ck4[j] = c[bb * NDIM + n] * K2LOG2E;
  }
  float sacc[8][4];
  #pragma unroll
  for (int i = 0; i < 8; i++)
    #pragma unroll
    for (int r = 0; r < 4; r++) sacc[i][r] = 0.f;
  #pragma unroll
  for (int i = 0; i < 8; i++)
    #pragma unroll
    for (int j = 0; j < 4; j++)
      #pragma unroll
      for (int r = 0; r < 4; r++) {
        float t = __builtin_fmaf(acc[i][j][r], K2LOG2E, ck4[j]);
        float e = __builtin_amdgcn_exp2f(t);        // inf->rcp 0 (tanh=1); 0 (tanh=-1)
        float rr = __builtin_amdgcn_rcpf(e + 1.f);
        sacc[i][r] = __builtin_fmaf(vw4[j], rr, sacc[i][r]);
      }

  // reduce over 16 n-lanes of each quad, then across the 4 n-waves via LDS.
  // sred overlays A-ring slot 0 (last read at tile-14 ph1-2, long freed).
  float* sred = (float*)shb;                      // 8 waves x 128 rows = 4 KB
  #pragma unroll
  for (int i = 0; i < 8; i++)
    #pragma unroll
    for (int r = 0; r < 4; r++) {
      float s = vws - 2.f * sacc[i][r];
      s += __shfl_xor(s, 1);
      s += __shfl_xor(s, 2);
      s += __shfl_xor(s, 4);
      s += __shfl_xor(s, 8);
      if (lrow == 0) sred[wave * 128 + i * 16 + lq * 4 + r] = s;
    }
  __syncthreads();
  if (tid < 256) {
    int mh = tid >> 7;            // which 128-row half -> waves mh*4 .. mh*4+3
    int ml = tid & 127;
    float v = sred[mh * 512 + ml] + sred[mh * 512 + 128 + ml]
            + sred[mh * 512 + 256 + ml] + sred[mh * 512 + 384 + ml];
    score[(size_t)nt * M_TOT + m0 + tid] = v;
  }
}

// ---------------- softmax over T per b; sums the NPART partial slices ------
__global__ __launch_bounds__(256) void softmax_kernel(float* __restrict__ sc,
                                                      float* __restrict__ wout) {
  const int b = blockIdx.x;
  const int tid = threadIdx.x;
  float4* s4 = (float4*)(sc + (size_t)b * TDIM);
  float4 v0 = s4[2*tid], v1 = s4[2*tid+1];
  #pragma unroll
  for (int k = 1; k < NPART; k++) {
    const float4* p4 = (const float4*)(sc + (size_t)k * M_TOT + (size_t)b * TDIM);
    float4 u0 = p4[2*tid], u1 = p4[2*tid+1];
    v0.x += u0.x; v0.y += u0.y; v0.z += u0.z; v0.w += u0.w;
    v1.x += u1.x; v1.y += u1.y; v1.z += u1.z; v1.w += u1.w;
  }
  float mx = fmaxf(fmaxf(fmaxf(v0.x,v0.y),fmaxf(v0.z,v0.w)),
                   fmaxf(fmaxf(v1.x,v1.y),fmaxf(v1.z,v1.w)));
  #pragma unroll
  for (int off = 32; off > 0; off >>= 1) mx = fmaxf(mx, __shfl_xor(mx, off));
  __shared__ float redm[4];
  __shared__ float reds[4];
  if ((tid & 63) == 0) redm[tid >> 6] = mx;
  __syncthreads();
  mx = fmaxf(fmaxf(redm[0], redm[1]), fmaxf(redm[2], redm[3]));
  v0.x = __expf(v0.x - mx); v0.y = __expf(v0.y - mx);
  v0.z = __expf(v0.z - mx); v0.w = __expf(v0.w - mx);
  v1.x = __expf(v1.x - mx); v1.y = __expf(v1.y - mx);
  v1.z = __expf(v1.z - mx); v1.w = __expf(v1.w - mx);
  float sum = v0.x+v0.y+v0.z+v0.w+v1.x+v1.y+v1.z+v1.w;
  #pragma unroll
  for (int off = 32; off > 0; off >>= 1) sum += __shfl_xor(sum, off);
  if ((tid & 63) == 0) reds[tid >> 6] = sum;
  __syncthreads();
  sum = reds[0]+reds[1]+reds[2]+reds[3];
  float inv = 1.f / sum;
  v0.x *= inv; v0.y *= inv; v0.z *= inv; v0.w *= inv;
  v1.x *= inv; v1.y *= inv; v1.z *= inv; v1.w *= inv;
  s4[2*tid] = v0; s4[2*tid+1] = v1;                 // ws copy for context pass
  float4* w4 = (float4*)(wout + (size_t)b * TDIM);  // d_out weights
  w4[2*tid] = v0; w4[2*tid+1] = v1;
}

// ---------------- context[b,u] = sum_t w[b,t]*x[b,t,u]  (exact, no atomics) -
// grid (8 u-chunks of 128, 32 b); 256 threads = 16 u-threads x 16 t-rows
__global__ __launch_bounds__(256) void context_kernel(const ushort* __restrict__ xb,
                                                      const float* __restrict__ wgt,
                                                      float* __restrict__ ctx) {
  const int uc = blockIdx.x;
  const int b = blockIdx.y;
  const int tid = threadIdx.x;
  __shared__ float wl[TDIM];
  {
    const float4* wsrc = (const float4*)(wgt + (size_t)b * TDIM);
    float4* wdst = (float4*)wl;
    wdst[tid] = wsrc[tid];
    wdst[tid + 256] = wsrc[tid + 256];
  }
  __syncthreads();
  const int ut = tid & 15;         // 16 threads x ushort8 = 128 u
  const int tr = tid >> 4;         // 16 t-rows per sweep
  const ushort* xp = xb + (size_t)b * TDIM * UNITS + uc * 128 + ut * 8;
  float a8[8];
  #pragma unroll
  for (int e = 0; e < 8; e++) a8[e] = 0.f;
  for (int t = tr; t < TDIM; t += 64) {            // 4-way unrolled over stride 16
    ushort8 x0 = *(const ushort8*)(xp + (size_t)(t     ) * UNITS);
    ushort8 x1 = *(const ushort8*)(xp + (size_t)(t + 16) * UNITS);
    ushort8 x2 = *(const ushort8*)(xp + (size_t)(t + 32) * UNITS);
    ushort8 x3 = *(const ushort8*)(xp + (size_t)(t + 48) * UNITS);
    float w0 = wl[t], w1 = wl[t+16], w2 = wl[t+32], w3 = wl[t+48];
    #pragma unroll
    for (int e = 0; e < 8; e++) {
      a8[e] += w0 * bf2f(x0[e]);
      a8[e] += w1 * bf2f(x1[e]);
      a8[e] += w2 * bf2f(x2[e]);
      a8[e] += w3 * bf2f(x3[e]);
    }
  }
  // reduce over the 4 t-rows within each wave
  #pragma unroll
  for (int e = 0; e < 8; e++) {
    a8[e] += __shfl_xor(a8[e], 16);
    a8[e] += __shfl_xor(a8[e], 32);
  }
  __shared__ float red[512];
  const int wave = tid >> 6;
  const int l = tid & 63;
  if (l < 16) {
    #pragma unroll
    for (int e = 0; e < 8; e++) red[wave * 128 + l * 8 + e] = a8[e];
  }
  __syncthreads();
  if (tid < 128) {
    float v = red[tid] + red[128 + tid] + red[256 + tid] + red[384 + tid];
    ctx[(size_t)b * UNITS + uc * 128 + tid] = v;
  }
}

extern "C" void kernel_launch(void* const* d_in, const int* in_sizes, int n_in,
                              void* d_out, int out_size, void* d_ws, size_t ws_size,
                              hipStream_t stream) {
  const float* x   = (const float*)d_in[0];
  const float* hid = (const float*)d_in[1];
  const float* W1w = (const float*)d_in[2];
  const float* W1b = (const float*)d_in[3];
  const float* W2w = (const float*)d_in[4];
  const float* W2b = (const float*)d_in[5];
  const float* Vw  = (const float*)d_in[6];
  // d_in[7] (V_b) intentionally unused: softmax is shift-invariant.
  float* out = (float*)d_out;

  char* ws = (char*)d_ws;
  ushort* xb   = (ushort*)ws;                                        // 128 MB
  ushort* w1b  = (ushort*)(ws + (size_t)M_TOT*KDIM*2);               // 2 MB
  float*  cbuf = (float*)(ws + (size_t)M_TOT*KDIM*2 + (size_t)NDIM*KDIM*2); // 128 KB
  float*  score= (float*)((char*)cbuf + (size_t)BDIM*NDIM*4);        // NPART x 256 KB partials

  cvt_kernel<<<4096, 256, 0, stream>>>(x, xb, M_TOT*KDIM/8);
  cvt_kernel<<<512, 256, 0, stream>>>(W1w, w1b, NDIM*KDIM/8);
  prep_c_kernel<<<NDIM, 64, 0, stream>>>(W2w, hid, W1b, W2b, cbuf);
  gemm_score_kernel<<<M_TOT/256 * NPART, 512, 0, stream>>>(xb, w1b, cbuf, Vw, score);
  softmax_kernel<<<BDIM, 256, 0, stream>>>(score, out + (size_t)BDIM*UNITS);
  context_kernel<<<dim3(8, BDIM), 256, 0, stream>>>(xb, score, out);
}